// Round 7
// baseline (240.427 us; speedup 1.0000x reference)
//
#include <hip/hip_runtime.h>
#include <hip/hip_bf16.h>
#include <cstdint>
#include <cstddef>
#include <type_traits>

// FocalAttention: B=4 T=2048 D=1024 H=16 hd=64 RADIUS=4 (banded, 9-wide window)
// fp32 in/out. cvt(fp32->bf16) -> GEMM1 x2 M-halves (qkv in [b,h,s,t,d] layout)
// -> banded attn -> GEMM2 128x128 (fp32 out).
// GEMMs: BK=64, XOR-swizzled LDS (0 bank conflicts, verified r4).
// GEMM1 split in two M-halves: diagnostic (top-5 counter slots) + tail overlap.

typedef __hip_bfloat16 bf16;
typedef __attribute__((ext_vector_type(8))) short bf16x8;   // A/B frag: 8 bf16 = 4 VGPRs
typedef __attribute__((ext_vector_type(4))) float f32x4;    // C/D frag
typedef __attribute__((ext_vector_type(8))) unsigned short u16x8;

#define BATCH  4
#define SEQ    2048
#define DIM    1024
#define NHEAD  16
#define HDIM   64
#define RADIUS 4
#define ROWS   (BATCH * SEQ)          // 8192
#define KDIM   1024
#define HSLICE (SEQ * HDIM)           // elems per (b,h,s) slice

__device__ __forceinline__ void async_copy16(const void* gptr, void* lptr) {
    __builtin_amdgcn_global_load_lds(
        (const __attribute__((address_space(1))) unsigned int*)(uintptr_t)gptr,
        (__attribute__((address_space(3))) unsigned int*)(uint32_t)(uintptr_t)lptr,
        16, 0, 0);
}

// Fused fp32 -> bf16 convert for all three tensors, 8 elems/thread.
__global__ __launch_bounds__(256)
void cvt_all(const float* __restrict__ s1, bf16* __restrict__ d1, int n1,
             const float* __restrict__ s2, bf16* __restrict__ d2, int n2,
             const float* __restrict__ s3, bf16* __restrict__ d3, int n3) {
    int i = blockIdx.x * blockDim.x + threadIdx.x;
    const float* src; bf16* dst;
    if (i < n1)              { src = s1; dst = d1; }
    else if (i < n1 + n2)    { i -= n1; src = s2; dst = d2; }
    else if (i < n1+n2+n3)   { i -= n1 + n2; src = s3; dst = d3; }
    else return;
    const float4 a = ((const float4*)src)[2 * i];
    const float4 b = ((const float4*)src)[2 * i + 1];
    union { u16x8 v; __hip_bfloat16 h[8]; } o;
    o.h[0] = __float2bfloat16(a.x); o.h[1] = __float2bfloat16(a.y);
    o.h[2] = __float2bfloat16(a.z); o.h[3] = __float2bfloat16(a.w);
    o.h[4] = __float2bfloat16(b.x); o.h[5] = __float2bfloat16(b.y);
    o.h[6] = __float2bfloat16(b.z); o.h[7] = __float2bfloat16(b.w);
    ((u16x8*)dst)[i] = o.v;
}

// C = A[M,K]*B[N,K]^T + bias. 128x128 tile, BK=64, XOR-swizzled LDS.
// QKV_LAYOUT=true writes [b,h,s,t,d] with global row = row0 + local row.
template <int NMAT, typename OutT, bool QKV_LAYOUT>
__global__ __launch_bounds__(256)
void gemm_bt_bias(const bf16* __restrict__ A, const bf16* __restrict__ B,
                  const float* __restrict__ bias, OutT* __restrict__ C, int row0) {
    __shared__ bf16 As[128 * 64];   // 16 KB
    __shared__ bf16 Bs[128 * 64];   // 16 KB

    const int tid  = threadIdx.x;
    const int lane = tid & 63;
    const int wave = tid >> 6;
    const int quad = lane >> 4;
    const int l16  = lane & 15;

    const int tileM = blockIdx.y * 128;
    const int tileN = blockIdx.x * 128;
    const int wm = (wave >> 1) * 64;
    const int wn = (wave & 1) * 64;

    f32x4 acc[4][4] = {};

    for (int kt = 0; kt < KDIM; kt += 64) {
        #pragma unroll
        for (int i = 0; i < 4; ++i) {
            const int c   = i * 256 + tid;
            const int row = c >> 3;
            const int kg  = (c & 7) ^ (row & 7);   // XOR swizzle (bank-conflict-free reads)
            async_copy16(A + (size_t)(tileM + row) * KDIM + kt + kg * 8,
                         (char*)As + c * 16);
            async_copy16(B + (size_t)(tileN + row) * KDIM + kt + kg * 8,
                         (char*)Bs + c * 16);
        }
        __syncthreads();

        #pragma unroll
        for (int ks = 0; ks < 2; ++ks) {
            const int kq = ks * 4 + quad;
            const int so = (kq ^ (l16 & 7)) * 8;
            bf16x8 aF[4], bF[4];
            #pragma unroll
            for (int mt = 0; mt < 4; ++mt)
                aF[mt] = *(const bf16x8*)(As + (wm + mt * 16 + l16) * 64 + so);
            #pragma unroll
            for (int nt = 0; nt < 4; ++nt)
                bF[nt] = *(const bf16x8*)(Bs + (wn + nt * 16 + l16) * 64 + so);

            #pragma unroll
            for (int mt = 0; mt < 4; ++mt)
                #pragma unroll
                for (int nt = 0; nt < 4; ++nt)
                    acc[mt][nt] = __builtin_amdgcn_mfma_f32_16x16x32_bf16(
                        aF[mt], bF[nt], acc[mt][nt], 0, 0, 0);
        }
        __syncthreads();
    }

    // epilogue: C/D layout col = lane&15, row = quad*4 + reg  [m89/m91-verified]
    #pragma unroll
    for (int nt = 0; nt < 4; ++nt) {
        const int scol = tileN + wn + nt * 16;
        const float bv = bias[scol + l16];
        #pragma unroll
        for (int mt = 0; mt < 4; ++mt) {
            #pragma unroll
            for (int r = 0; r < 4; ++r) {
                const int rowg = row0 + tileM + wm + mt * 16 + quad * 4 + r;
                const float v = acc[mt][nt][r] + bv;
                if constexpr (QKV_LAYOUT) {
                    const int s = scol >> 10;
                    const int h = (scol >> 6) & (NHEAD - 1);
                    const int d = (scol & 63) + l16;
                    const int b = rowg >> 11;
                    const int t = rowg & (SEQ - 1);
                    ((bf16*)C)[(size_t)((b * NHEAD + h) * 3 + s) * HSLICE
                               + (size_t)t * HDIM + d] = __float2bfloat16(v);
                } else if constexpr (std::is_same<OutT, float>::value) {
                    C[(size_t)rowg * NMAT + scol + l16] = v;
                } else {
                    C[(size_t)rowg * NMAT + scol + l16] = __float2bfloat16(v);
                }
            }
        }
    }
}

// ---- 8 bf16 (as uint4) -> 8 floats
__device__ __forceinline__ void bf8_to_f32(const uint4 u, float* f) {
    union { uint32_t u; float f; } c;
    c.u = u.x << 16;         f[0] = c.f;
    c.u = u.x & 0xffff0000u; f[1] = c.f;
    c.u = u.y << 16;         f[2] = c.f;
    c.u = u.y & 0xffff0000u; f[3] = c.f;
    c.u = u.z << 16;         f[4] = c.f;
    c.u = u.z & 0xffff0000u; f[5] = c.f;
    c.u = u.w << 16;         f[6] = c.f;
    c.u = u.w & 0xffff0000u; f[7] = c.f;
}

// Banded attention over [b,h,s,t,d] qkv. Block=256 covers 128 queries of one (b,h).
__global__ __launch_bounds__(256)
void attn_banded3(const bf16* __restrict__ qkv, bf16* __restrict__ aout) {
    const int tid = threadIdx.x;
    const int qi  = tid >> 1;
    const int hf  = tid & 1;
    const int t0  = blockIdx.x * 128;
    const int h   = blockIdx.y;
    const int b   = blockIdx.z;
    const int t   = t0 + qi;

    const size_t bh3 = (size_t)(b * NHEAD + h) * 3;
    const bf16* qb = qkv + (bh3 + 0) * HSLICE + (size_t)t * HDIM + hf * 32;
    const bf16* kb = qkv + (bh3 + 1) * HSLICE + hf * 32;
    const bf16* vb = qkv + (bh3 + 2) * HSLICE + hf * 32;
    const float scale = 0.125f;

    float q32[32];
    {
        const uint4* qp = (const uint4*)qb;
        uint4 u0 = qp[0], u1 = qp[1], u2 = qp[2], u3 = qp[3];
        bf8_to_f32(u0, q32 + 0);  bf8_to_f32(u1, q32 + 8);
        bf8_to_f32(u2, q32 + 16); bf8_to_f32(u3, q32 + 24);
    }

    float sc[2 * RADIUS + 1];
    #pragma unroll
    for (int j = 0; j < 2 * RADIUS + 1; ++j) {
        const int k = t - RADIUS + j;
        const bool valid = (k >= 0) && (k < SEQ);
        const int kc = valid ? k : t;
        const uint4* kp = (const uint4*)(kb + (size_t)kc * HDIM);
        float kf[32];
        uint4 u0 = kp[0], u1 = kp[1], u2 = kp[2], u3 = kp[3];
        bf8_to_f32(u0, kf + 0);  bf8_to_f32(u1, kf + 8);
        bf8_to_f32(u2, kf + 16); bf8_to_f32(u3, kf + 24);
        float p = 0.f;
        #pragma unroll
        for (int e = 0; e < 32; ++e) p = fmaf(q32[e], kf[e], p);
        p += __shfl_xor(p, 1, 64);
        sc[j] = valid ? p * scale : -1e30f;
    }

    float mx = sc[0];
    #pragma unroll
    for (int j = 1; j < 2 * RADIUS + 1; ++j) mx = fmaxf(mx, sc[j]);
    float sum = 0.f;
    #pragma unroll
    for (int j = 0; j < 2 * RADIUS + 1; ++j) { sc[j] = __expf(sc[j] - mx); sum += sc[j]; }
    const float inv = 1.0f / sum;

    float o32[32];
    #pragma unroll
    for (int e = 0; e < 32; ++e) o32[e] = 0.f;
    #pragma unroll
    for (int j = 0; j < 2 * RADIUS + 1; ++j) {
        const int k = t - RADIUS + j;
        const int kc = (k >= 0 && k < SEQ) ? k : t;
        const uint4* vp = (const uint4*)(vb + (size_t)kc * HDIM);
        float vf[32];
        uint4 u0 = vp[0], u1 = vp[1], u2 = vp[2], u3 = vp[3];
        bf8_to_f32(u0, vf + 0);  bf8_to_f32(u1, vf + 8);
        bf8_to_f32(u2, vf + 16); bf8_to_f32(u3, vf + 24);
        const float w = sc[j];
        #pragma unroll
        for (int e = 0; e < 32; ++e) o32[e] = fmaf(w, vf[e], o32[e]);
    }

    bf16* op = aout + ((size_t)b * SEQ + t) * DIM + h * HDIM + hf * 32;
    #pragma unroll
    for (int c = 0; c < 4; ++c) {
        union { u16x8 v; __hip_bfloat16 hh[8]; } o;
        #pragma unroll
        for (int e = 0; e < 8; ++e) o.hh[e] = __float2bfloat16(o32[c * 8 + e] * inv);
        ((u16x8*)op)[c] = o.v;
    }
}

extern "C" void kernel_launch(void* const* d_in, const int* in_sizes, int n_in,
                              void* d_out, int out_size, void* d_ws, size_t ws_size,
                              hipStream_t stream) {
    const float* x      = (const float*)d_in[0];
    const float* w_qkv  = (const float*)d_in[1];
    const float* b_qkv  = (const float*)d_in[2];
    const float* w_proj = (const float*)d_in[3];
    const float* b_proj = (const float*)d_in[4];
    float* out = (float*)d_out;

    bf16* xb     = (bf16*)d_ws;
    bf16* wqkvb  = xb + (size_t)ROWS * DIM;
    bf16* wprojb = wqkvb + (size_t)3072 * 1024;
    bf16* qkvb   = wprojb + (size_t)1024 * 1024;   // [b,h,s,t,d], 48 MiB
    bf16* attnb  = qkvb + (size_t)ROWS * 3072;

    const int n1 = ROWS * DIM / 8, n2 = 3072 * 1024 / 8, n3 = 1024 * 1024 / 8;
    cvt_all<<<(n1 + n2 + n3 + 255) / 256, 256, 0, stream>>>(x, xb, n1, w_qkv, wqkvb, n2,
                                                            w_proj, wprojb, n3);

    // GEMM1 in two M-halves (diagnostic split: each ~36-38 us frees top-5 slots)
    const int HALF = ROWS / 2;   // 4096
    gemm_bt_bias<3072, bf16, true><<<dim3(3072 / 128, HALF / 128), 256, 0, stream>>>(
        xb, wqkvb, b_qkv, qkvb, 0);
    gemm_bt_bias<3072, bf16, true><<<dim3(3072 / 128, HALF / 128), 256, 0, stream>>>(
        xb + (size_t)HALF * KDIM, wqkvb, b_qkv, qkvb, HALF);

    attn_banded3<<<dim3(SEQ / 128, NHEAD, BATCH), 256, 0, stream>>>(qkvb, attnb);

    // GEMM2: 128x128 tiles (r6 m64 variant regressed; reverted)
    gemm_bt_bias<1024, float, false><<<dim3(1024 / 128, ROWS / 128), 256, 0, stream>>>(
        attnb, wprojb, b_proj, out, 0);
}

// Round 8
// 201.629 us; speedup vs baseline: 1.1924x; 1.1924x over previous
//
#include <hip/hip_runtime.h>
#include <hip/hip_bf16.h>
#include <cstdint>
#include <cstddef>
#include <type_traits>

// FocalAttention: B=4 T=2048 D=1024 H=16 hd=64 RADIUS=4 (banded, 9-wide window)
// fp32 in/out. cvt(fp32->bf16) -> gemm_qkv (qkv in [b,h,s,t,d] layout) -> banded attn
// (4 threads/query, 32 waves/CU) -> gemm_proj 128x128 (fp32 out).
// GEMMs: 128x128 tile, BK=64, XOR-swizzled LDS (0 bank conflicts, verified r4).
// r7 lesson: never split the GEMM grid below ~4 blocks/CU (768-block halves ran 560 TF).

typedef __hip_bfloat16 bf16;
typedef __attribute__((ext_vector_type(8))) short bf16x8;   // A/B frag: 8 bf16 = 4 VGPRs
typedef __attribute__((ext_vector_type(4))) float f32x4;    // C/D frag
typedef __attribute__((ext_vector_type(8))) unsigned short u16x8;

#define BATCH  4
#define SEQ    2048
#define DIM    1024
#define NHEAD  16
#define HDIM   64
#define RADIUS 4
#define ROWS   (BATCH * SEQ)          // 8192
#define KDIM   1024
#define HSLICE (SEQ * HDIM)           // elems per (b,h,s) slice

__device__ __forceinline__ void async_copy16(const void* gptr, void* lptr) {
    __builtin_amdgcn_global_load_lds(
        (const __attribute__((address_space(1))) unsigned int*)(uintptr_t)gptr,
        (__attribute__((address_space(3))) unsigned int*)(uint32_t)(uintptr_t)lptr,
        16, 0, 0);
}

// Fused fp32 -> bf16 convert for all three tensors, 8 elems/thread.
__global__ __launch_bounds__(256)
void cvt_all(const float* __restrict__ s1, bf16* __restrict__ d1, int n1,
             const float* __restrict__ s2, bf16* __restrict__ d2, int n2,
             const float* __restrict__ s3, bf16* __restrict__ d3, int n3) {
    int i = blockIdx.x * blockDim.x + threadIdx.x;
    const float* src; bf16* dst;
    if (i < n1)              { src = s1; dst = d1; }
    else if (i < n1 + n2)    { i -= n1; src = s2; dst = d2; }
    else if (i < n1+n2+n3)   { i -= n1 + n2; src = s3; dst = d3; }
    else return;
    const float4 a = ((const float4*)src)[2 * i];
    const float4 b = ((const float4*)src)[2 * i + 1];
    union { u16x8 v; __hip_bfloat16 h[8]; } o;
    o.h[0] = __float2bfloat16(a.x); o.h[1] = __float2bfloat16(a.y);
    o.h[2] = __float2bfloat16(a.z); o.h[3] = __float2bfloat16(a.w);
    o.h[4] = __float2bfloat16(b.x); o.h[5] = __float2bfloat16(b.y);
    o.h[6] = __float2bfloat16(b.z); o.h[7] = __float2bfloat16(b.w);
    ((u16x8*)dst)[i] = o.v;
}

// Shared GEMM body: C = A[M,K]*B[N,K]^T + bias. 128x128 tile, BK=64, XOR swizzle.
template <int NMAT, typename OutT, bool QKV_LAYOUT>
__device__ __forceinline__
void gemm_body(const bf16* __restrict__ A, const bf16* __restrict__ B,
               const float* __restrict__ bias, OutT* __restrict__ C) {
    __shared__ bf16 As[128 * 64];   // 16 KB
    __shared__ bf16 Bs[128 * 64];   // 16 KB

    const int tid  = threadIdx.x;
    const int lane = tid & 63;
    const int wave = tid >> 6;
    const int quad = lane >> 4;
    const int l16  = lane & 15;

    const int tileM = blockIdx.y * 128;
    const int tileN = blockIdx.x * 128;
    const int wm = (wave >> 1) * 64;
    const int wn = (wave & 1) * 64;

    f32x4 acc[4][4] = {};

    for (int kt = 0; kt < KDIM; kt += 64) {
        #pragma unroll
        for (int i = 0; i < 4; ++i) {
            const int c   = i * 256 + tid;
            const int row = c >> 3;
            const int kg  = (c & 7) ^ (row & 7);   // XOR swizzle (bank-conflict-free reads)
            async_copy16(A + (size_t)(tileM + row) * KDIM + kt + kg * 8,
                         (char*)As + c * 16);
            async_copy16(B + (size_t)(tileN + row) * KDIM + kt + kg * 8,
                         (char*)Bs + c * 16);
        }
        __syncthreads();

        #pragma unroll
        for (int ks = 0; ks < 2; ++ks) {
            const int kq = ks * 4 + quad;
            const int so = (kq ^ (l16 & 7)) * 8;
            bf16x8 aF[4], bF[4];
            #pragma unroll
            for (int mt = 0; mt < 4; ++mt)
                aF[mt] = *(const bf16x8*)(As + (wm + mt * 16 + l16) * 64 + so);
            #pragma unroll
            for (int nt = 0; nt < 4; ++nt)
                bF[nt] = *(const bf16x8*)(Bs + (wn + nt * 16 + l16) * 64 + so);

            #pragma unroll
            for (int mt = 0; mt < 4; ++mt)
                #pragma unroll
                for (int nt = 0; nt < 4; ++nt)
                    acc[mt][nt] = __builtin_amdgcn_mfma_f32_16x16x32_bf16(
                        aF[mt], bF[nt], acc[mt][nt], 0, 0, 0);
        }
        __syncthreads();
    }

    // epilogue: C/D layout col = lane&15, row = quad*4 + reg  [m89/m91-verified]
    #pragma unroll
    for (int nt = 0; nt < 4; ++nt) {
        const int scol = tileN + wn + nt * 16;
        const float bv = bias[scol + l16];
        #pragma unroll
        for (int mt = 0; mt < 4; ++mt) {
            #pragma unroll
            for (int r = 0; r < 4; ++r) {
                const int rowg = tileM + wm + mt * 16 + quad * 4 + r;
                const float v = acc[mt][nt][r] + bv;
                if constexpr (QKV_LAYOUT) {
                    const int s = scol >> 10;
                    const int h = (scol >> 6) & (NHEAD - 1);
                    const int d = (scol & 63) + l16;
                    const int b = rowg >> 11;
                    const int t = rowg & (SEQ - 1);
                    ((bf16*)C)[(size_t)((b * NHEAD + h) * 3 + s) * HSLICE
                               + (size_t)t * HDIM + d] = __float2bfloat16(v);
                } else if constexpr (std::is_same<OutT, float>::value) {
                    C[(size_t)rowg * NMAT + scol + l16] = v;
                } else {
                    C[(size_t)rowg * NMAT + scol + l16] = __float2bfloat16(v);
                }
            }
        }
    }
}

// Distinct kernel names so rocprof rows are attributable per stage.
__global__ __launch_bounds__(256)
void gemm_qkv(const bf16* __restrict__ A, const bf16* __restrict__ B,
              const float* __restrict__ bias, bf16* __restrict__ C) {
    gemm_body<3072, bf16, true>(A, B, bias, C);
}

__global__ __launch_bounds__(256)
void gemm_proj(const bf16* __restrict__ A, const bf16* __restrict__ B,
               const float* __restrict__ bias, float* __restrict__ C) {
    gemm_body<1024, float, false>(A, B, bias, C);
}

// ---- 8 bf16 (as uint4) -> 8 floats
__device__ __forceinline__ void bf8_to_f32(const uint4 u, float* f) {
    union { uint32_t u; float f; } c;
    c.u = u.x << 16;         f[0] = c.f;
    c.u = u.x & 0xffff0000u; f[1] = c.f;
    c.u = u.y << 16;         f[2] = c.f;
    c.u = u.y & 0xffff0000u; f[3] = c.f;
    c.u = u.z << 16;         f[4] = c.f;
    c.u = u.z & 0xffff0000u; f[5] = c.f;
    c.u = u.w << 16;         f[6] = c.f;
    c.u = u.w & 0xffff0000u; f[7] = c.f;
}

// Banded attention v4 over [b,h,s,t,d] qkv: 4 threads/query (16 dims each).
// Block 256 = 64 queries; grid (SEQ/64, NHEAD, BATCH) = 8192 waves = 32/CU.
// Scores merged across the 4-lane group via shfl_xor(1)+shfl_xor(2).
__global__ __launch_bounds__(256)
void attn_banded4(const bf16* __restrict__ qkv, bf16* __restrict__ aout) {
    const int tid = threadIdx.x;
    const int qi  = tid >> 2;          // 0..63
    const int ch  = tid & 3;           // 16-dim chunk
    const int t   = blockIdx.x * 64 + qi;
    const int h   = blockIdx.y;
    const int b   = blockIdx.z;

    const size_t bh3 = (size_t)(b * NHEAD + h) * 3;
    const bf16* qb = qkv + (bh3 + 0) * HSLICE + (size_t)t * HDIM + ch * 16;
    const bf16* kb = qkv + (bh3 + 1) * HSLICE + ch * 16;
    const bf16* vb = qkv + (bh3 + 2) * HSLICE + ch * 16;
    const float scale = 0.125f;        // hd^-0.5

    float q16[16];
    {
        const uint4* qp = (const uint4*)qb;
        uint4 u0 = qp[0], u1 = qp[1];
        bf8_to_f32(u0, q16); bf8_to_f32(u1, q16 + 8);
    }

    float sc[2 * RADIUS + 1];
    #pragma unroll
    for (int j = 0; j < 2 * RADIUS + 1; ++j) {
        const int k = t - RADIUS + j;
        const bool valid = (k >= 0) && (k < SEQ);
        const int kc = valid ? k : t;
        const uint4* kp = (const uint4*)(kb + (size_t)kc * HDIM);
        float kf[16];
        uint4 u0 = kp[0], u1 = kp[1];
        bf8_to_f32(u0, kf); bf8_to_f32(u1, kf + 8);
        float p = 0.f;
        #pragma unroll
        for (int e = 0; e < 16; ++e) p = fmaf(q16[e], kf[e], p);
        p += __shfl_xor(p, 1, 64);     // merge 4 chunks
        p += __shfl_xor(p, 2, 64);
        sc[j] = valid ? p * scale : -1e30f;
    }

    float mx = sc[0];
    #pragma unroll
    for (int j = 1; j < 2 * RADIUS + 1; ++j) mx = fmaxf(mx, sc[j]);
    float sum = 0.f;
    #pragma unroll
    for (int j = 0; j < 2 * RADIUS + 1; ++j) { sc[j] = __expf(sc[j] - mx); sum += sc[j]; }
    const float inv = 1.0f / sum;

    float o16[16];
    #pragma unroll
    for (int e = 0; e < 16; ++e) o16[e] = 0.f;
    #pragma unroll
    for (int j = 0; j < 2 * RADIUS + 1; ++j) {
        const int k = t - RADIUS + j;
        const int kc = (k >= 0 && k < SEQ) ? k : t;   // weight ~0 when clamped
        const uint4* vp = (const uint4*)(vb + (size_t)kc * HDIM);
        float vf[16];
        uint4 u0 = vp[0], u1 = vp[1];
        bf8_to_f32(u0, vf); bf8_to_f32(u1, vf + 8);
        const float w = sc[j];
        #pragma unroll
        for (int e = 0; e < 16; ++e) o16[e] = fmaf(w, vf[e], o16[e]);
    }

    bf16* op = aout + ((size_t)b * SEQ + t) * DIM + h * HDIM + ch * 16;
    #pragma unroll
    for (int c2 = 0; c2 < 2; ++c2) {
        union { u16x8 v; __hip_bfloat16 hh[8]; } o;
        #pragma unroll
        for (int e = 0; e < 8; ++e) o.hh[e] = __float2bfloat16(o16[c2 * 8 + e] * inv);
        ((u16x8*)op)[c2] = o.v;
    }
}

extern "C" void kernel_launch(void* const* d_in, const int* in_sizes, int n_in,
                              void* d_out, int out_size, void* d_ws, size_t ws_size,
                              hipStream_t stream) {
    const float* x      = (const float*)d_in[0];
    const float* w_qkv  = (const float*)d_in[1];
    const float* b_qkv  = (const float*)d_in[2];
    const float* w_proj = (const float*)d_in[3];
    const float* b_proj = (const float*)d_in[4];
    float* out = (float*)d_out;

    bf16* xb     = (bf16*)d_ws;
    bf16* wqkvb  = xb + (size_t)ROWS * DIM;
    bf16* wprojb = wqkvb + (size_t)3072 * 1024;
    bf16* qkvb   = wprojb + (size_t)1024 * 1024;   // [b,h,s,t,d], 48 MiB
    bf16* attnb  = qkvb + (size_t)ROWS * 3072;

    const int n1 = ROWS * DIM / 8, n2 = 3072 * 1024 / 8, n3 = 1024 * 1024 / 8;
    cvt_all<<<(n1 + n2 + n3 + 255) / 256, 256, 0, stream>>>(x, xb, n1, w_qkv, wqkvb, n2,
                                                            w_proj, wprojb, n3);

    // GEMM1: single 1536-block launch (r7 split regressed; reverted)
    gemm_qkv<<<dim3(3072 / 128, ROWS / 128), 256, 0, stream>>>(xb, wqkvb, b_qkv, qkvb);

    // attn v4: 4 threads/query, 32 waves/CU
    attn_banded4<<<dim3(SEQ / 64, NHEAD, BATCH), 256, 0, stream>>>(qkvb, attnb);

    // GEMM2: 128x128 tiles, 512 blocks
    gemm_proj<<<dim3(1024 / 128, ROWS / 128), 256, 0, stream>>>(attnb, wprojb, b_proj, out);
}